// Round 4
// baseline (270.873 us; speedup 1.0000x reference)
//
#include <hip/hip_runtime.h>
#include <hip/hip_bf16.h>

typedef float f32x4 __attribute__((ext_vector_type(4)));
typedef __bf16 bf16x8 __attribute__((ext_vector_type(8)));

__device__ __forceinline__ unsigned short f2bf(float f) {
    unsigned u = __float_as_uint(f);
    return (unsigned short)((u + 0x7fffu + ((u >> 16) & 1u)) >> 16);  // RNE
}

// ---------------------------------------------------------------------------
// Elementwise fp32 -> bf16 (n multiple of 1024).
// ---------------------------------------------------------------------------
__global__ __launch_bounds__(256) void convert_bf16(
    const float* __restrict__ in, unsigned short* __restrict__ out)
{
    int i = (blockIdx.x * 256 + threadIdx.x) * 4;
    float4 v = *(const float4*)(in + i);
    ushort4 o = { f2bf(v.x), f2bf(v.y), f2bf(v.z), f2bf(v.w) };
    *(ushort4*)(out + i) = o;
}

// ---------------------------------------------------------------------------
// W [K,N] fp32 row-major  ->  Wt [N,K] bf16 row-major. 64x64 LDS tiles.
// ---------------------------------------------------------------------------
__global__ __launch_bounds__(256) void transpose_convert(
    const float* __restrict__ W, unsigned short* __restrict__ Wt, int K, int N)
{
    __shared__ float tile[64][65];
    const int bx = blockIdx.x;   // n tile
    const int by = blockIdx.y;   // k tile
    const int t = threadIdx.x;
    const int col4 = t & 15;     // 16 float4 per row
    const int row  = t >> 4;     // 16 rows per pass

    #pragma unroll
    for (int i = 0; i < 4; ++i) {
        int r = row + i * 16;    // k within tile
        float4 v = *(const float4*)(W + (size_t)(by * 64 + r) * N + bx * 64 + col4 * 4);
        tile[r][col4 * 4 + 0] = v.x;
        tile[r][col4 * 4 + 1] = v.y;
        tile[r][col4 * 4 + 2] = v.z;
        tile[r][col4 * 4 + 3] = v.w;
    }
    __syncthreads();
    #pragma unroll
    for (int i = 0; i < 4; ++i) {
        int r = row + i * 16;    // n within tile
        ushort4 o = { f2bf(tile[col4 * 4 + 0][r]), f2bf(tile[col4 * 4 + 1][r]),
                      f2bf(tile[col4 * 4 + 2][r]), f2bf(tile[col4 * 4 + 3][r]) };
        *(ushort4*)(Wt + (size_t)(bx * 64 + r) * K + by * 64 + col4 * 4) = o;
    }
}

// ---------------------------------------------------------------------------
// bf16 MFMA GEMM (m97 structure): C = relu(A @ Bt^T + bias).
// A [M,K] bf16 row-major, Bt [N,K] bf16 row-major, 128x128 tile, BK=32,
// 256 threads = 4 waves (2x2), each wave 64x64 via 4x4 mfma_f32_16x16x32_bf16.
// ---------------------------------------------------------------------------
template <int OUT_BF16>
__global__ __launch_bounds__(256) void gemm_bf16_mfma(
    const unsigned short* __restrict__ A, const unsigned short* __restrict__ Bt,
    const float* __restrict__ bias, unsigned short* __restrict__ Cbf,
    float* __restrict__ Cf, int M, int N, int K)
{
    __shared__ unsigned short As[128 * 32];
    __shared__ unsigned short Bs[128 * 32];

    const int tid = threadIdx.x;
    const int wave = tid >> 6;
    const int lane = tid & 63;
    const int bn = blockIdx.x, bm = blockIdx.y;
    const int wm = (wave & 1) * 64;
    const int wn = (wave >> 1) * 64;

    const unsigned short* Ablk = A  + (size_t)(bm * 128) * K;
    const unsigned short* Bblk = Bt + (size_t)(bn * 128) * K;

    const int srow0 = wave * 32;
    const int lrow = lane >> 2;
    const int lcol = (lane & 3) * 8;

    f32x4 acc[4][4] = {};

    for (int k0 = 0; k0 < K; k0 += 32) {
        #pragma unroll
        for (int j = 0; j < 2; ++j) {
            int r = srow0 + j * 16 + lrow;
            __builtin_amdgcn_global_load_lds(
                (const __attribute__((address_space(1))) void*)(Ablk + (size_t)r * K + k0 + lcol),
                (__attribute__((address_space(3))) void*)(As + (srow0 + j * 16) * 32),
                16, 0, 0);
            __builtin_amdgcn_global_load_lds(
                (const __attribute__((address_space(1))) void*)(Bblk + (size_t)r * K + k0 + lcol),
                (__attribute__((address_space(3))) void*)(Bs + (srow0 + j * 16) * 32),
                16, 0, 0);
        }
        __syncthreads();

        bf16x8 a[4], b[4];
        #pragma unroll
        for (int mt = 0; mt < 4; ++mt)
            a[mt] = *(const bf16x8*)(As + (wm + mt * 16 + (lane & 15)) * 32 + (lane >> 4) * 8);
        #pragma unroll
        for (int nt = 0; nt < 4; ++nt)
            b[nt] = *(const bf16x8*)(Bs + (wn + nt * 16 + (lane & 15)) * 32 + (lane >> 4) * 8);
        #pragma unroll
        for (int mt = 0; mt < 4; ++mt)
            #pragma unroll
            for (int nt = 0; nt < 4; ++nt)
                acc[mt][nt] = __builtin_amdgcn_mfma_f32_16x16x32_bf16(
                    a[mt], b[nt], acc[mt][nt], 0, 0, 0);
        __syncthreads();
    }

    const int cm0 = bm * 128 + wm;
    const int cn0 = bn * 128 + wn;
    const int lc = lane & 15;
    const int lr = (lane >> 4) * 4;
    #pragma unroll
    for (int nt = 0; nt < 4; ++nt) {
        float bv = bias[cn0 + nt * 16 + lc];
        #pragma unroll
        for (int mt = 0; mt < 4; ++mt) {
            #pragma unroll
            for (int r = 0; r < 4; ++r) {
                float v = fmaxf(acc[mt][nt][r] + bv, 0.0f);
                size_t idx = (size_t)(cm0 + mt * 16 + lr + r) * N + cn0 + nt * 16 + lc;
                if (OUT_BF16) Cbf[idx] = f2bf(v);
                else          Cf[idx] = v;
            }
        }
    }
}

// ---------------------------------------------------------------------------
// Layer 3: scores[r] = dot(H[r,:], W3) + b3.  One wave per row, fp32.
// ---------------------------------------------------------------------------
__global__ __launch_bounds__(256) void matvec_bias(
    const float* __restrict__ H, const float* __restrict__ W,
    const float* __restrict__ b3, float* __restrict__ scores,
    float* __restrict__ out_scores, int N)
{
    const int wave = threadIdx.x >> 6;
    const int lane = threadIdx.x & 63;
    const int row  = blockIdx.x * 4 + wave;
    const float* h = H + (size_t)row * N;

    float s = 0.0f;
    for (int w = 0; w < N / 256; ++w) {
        float4 v = *(const float4*)(h + w * 256 + lane * 4);
        float4 g = *(const float4*)(W + w * 256 + lane * 4);
        s += v.x * g.x + v.y * g.y + v.z * g.z + v.w * g.w;
    }
    #pragma unroll
    for (int off = 32; off > 0; off >>= 1) s += __shfl_down(s, off);
    if (lane == 0) {
        float r = s + b3[0];
        scores[row] = r;
        out_scores[row] = r;
    }
}

// ---------------------------------------------------------------------------
// Stable-descending argsort position by brute-force counting.
// key = (desc_map(z) << 12) | i  -> distinct keys -> pos is a permutation;
// pos[i] = #{j : key_j < key_i}.  64 blocks x 64 lanes; each block caches all
// 4096 keys in LDS (broadcast reads), each lane counts for one i.
// ---------------------------------------------------------------------------
__global__ __launch_bounds__(64) void rank_count(
    const float* __restrict__ scores, int* __restrict__ posg)
{
    constexpr int n = 4096;
    __shared__ unsigned long long keys[n];   // 32 KB
    const int tid = threadIdx.x;
    const int i = blockIdx.x * 64 + tid;

    for (int t = tid; t < n; t += 64) {
        unsigned ub = __float_as_uint(scores[t]);
        unsigned m  = (ub & 0x80000000u) ? ~ub : (ub | 0x80000000u); // asc map
        unsigned d  = ~m;                                            // desc map
        keys[t] = ((unsigned long long)d << 12) | (unsigned)t;
    }
    __syncthreads();

    const unsigned long long mykey = keys[i];
    int cnt = 0;
    #pragma unroll 8
    for (int j = 0; j < n; ++j)
        cnt += (keys[j] < mykey) ? 1 : 0;
    posg[i] = cnt;
}

// ---------------------------------------------------------------------------
// PAV + fill, single block of 1024 threads.
//   svals[pos[i]] = z_i (LDS scatter) -> chunked PAV (64 chunks x 64, then
//   serial merge of block lists; PAV is associative over pooled blocks) ->
//   rank[i] = svals[pos[i]] - mean(block containing pos[i])  (coalesced).
// LDS: bsum f64[4096] 32K | svals f32[4096] 16K | bstart u16[4096] 8K |
//      plds u16[4096] 8K  = 64 KB exactly. nb broadcast via ws int.
// ---------------------------------------------------------------------------
__global__ __launch_bounds__(1024) void pav_fill(
    const float* __restrict__ scores, const int* __restrict__ posg,
    float* __restrict__ rank_out, int* nb_ws)
{
    constexpr int n = 4096;
    __shared__ __align__(16) unsigned char lds[65536];
    double* bsum  = (double*)lds;
    float*  svals = (float*)(lds + 32768);
    unsigned short* bstart = (unsigned short*)(lds + 49152);
    unsigned short* plds   = (unsigned short*)(lds + 57344);

    const int tid = threadIdx.x;

    for (int t = tid; t < n; t += 1024) {
        int p = posg[t];
        svals[p] = scores[t];
        plds[t] = (unsigned short)p;
    }
    __syncthreads();

    // ---- Phase A: per-chunk PAV, 64 threads, chunk c = tid ----
    if (tid < 64) {
        const int base = tid << 6;
        int depth = 0;
        double rtsum = 0.0; int rtstart = 0;
        for (int s = 0; s < 64; ++s) {
            int i = base + s;
            double csum = (double)svals[i] - (double)(n - i);   // y_i
            int cs = i;
            const int ce = i + 1;
            while (depth > 0) {
                if (rtsum * (double)(ce - cs) <= csum * (double)(cs - rtstart)) {
                    csum += rtsum; cs = rtstart; depth--;
                    if (depth > 0) {
                        rtsum = bsum[base + depth - 1];
                        rtstart = bstart[base + depth - 1];
                    }
                } else break;
            }
            if (depth > 0) {
                bsum[base + depth - 1] = rtsum;
                bstart[base + depth - 1] = (unsigned short)rtstart;
            }
            rtsum = csum; rtstart = cs; depth++;
        }
        bsum[base + depth - 1] = rtsum;
        bstart[base + depth - 1] = (unsigned short)rtstart;
        if (depth < 64) bstart[base + depth] = 0xFFFFu;   // sentinel
    }
    __syncthreads();

    // ---- Phase B: serial merge of chunk block lists (thread 0) ----
    if (tid == 0) {
        int g = 0;
        double gtsum = 0.0; int gtstart = 0;
        for (int c = 0; c < 64; ++c) {
            const int base = c << 6;
            for (int s = 0; s < 64; ++s) {
                const int r = base + s;
                int cs = bstart[r];
                if (cs == 0xFFFF) break;
                int ce;
                if (s < 63) {
                    int nx = bstart[r + 1];
                    ce = (nx == 0xFFFF) ? base + 64 : nx;
                } else ce = base + 64;
                double csum = bsum[r];
                while (g > 0) {
                    if (gtsum * (double)(ce - cs) <= csum * (double)(cs - gtstart)) {
                        csum += gtsum; cs = gtstart; g--;
                        if (g > 0) { gtsum = bsum[g - 1]; gtstart = bstart[g - 1]; }
                    } else break;
                }
                if (g > 0) {
                    bsum[g - 1] = gtsum;
                    bstart[g - 1] = (unsigned short)gtstart;
                }
                gtsum = csum; gtstart = cs; g++;
            }
        }
        bsum[g - 1] = gtsum;
        bstart[g - 1] = (unsigned short)gtstart;
        __hip_atomic_store(nb_ws, g, __ATOMIC_RELEASE, __HIP_MEMORY_SCOPE_AGENT);
    }
    __syncthreads();
    const int nb = __hip_atomic_load(nb_ws, __ATOMIC_ACQUIRE, __HIP_MEMORY_SCOPE_AGENT);

    // ---- gather: rank[i] = svals[p] - mean(block(p)), coalesced writes ----
    for (int t = tid; t < n; t += 1024) {
        int p = plds[t];
        int lo = 0, hi = nb - 1;
        while (lo < hi) {
            int mid = (lo + hi + 1) >> 1;
            if ((int)bstart[mid] <= p) lo = mid; else hi = mid - 1;
        }
        int bs = bstart[lo];
        int be = (lo + 1 < nb) ? (int)bstart[lo + 1] : n;
        float mean = (float)(bsum[lo] / (double)(be - bs));
        rank_out[t] = svals[p] - mean;
    }
}

// ---------------------------------------------------------------------------
extern "C" void kernel_launch(void* const* d_in, const int* in_sizes, int n_in,
                              void* d_out, int out_size, void* d_ws, size_t ws_size,
                              hipStream_t stream) {
    const float* x  = (const float*)d_in[0];
    const float* W1 = (const float*)d_in[1];
    const float* b1 = (const float*)d_in[2];
    const float* W2 = (const float*)d_in[3];
    const float* b2 = (const float*)d_in[4];
    const float* W3 = (const float*)d_in[5];
    const float* b3 = (const float*)d_in[6];
    float* out = (float*)d_out;   // [0,4096): rank, [4096,8192): scores

    const int B = 4096, D_IN = 512, H = 2048;

    char* ws = (char*)d_ws;
    unsigned short* h1  = (unsigned short*)(ws);                    // 16 MB bf16
    float*          h2  = (float*)(ws + (16u << 20));               // 32 MB fp32
    unsigned short* xb  = (unsigned short*)(ws + (48u << 20));      //  4 MB bf16
    unsigned short* W1t = (unsigned short*)(ws + (52u << 20));      //  2 MB bf16 [N,K]
    unsigned short* W2t = (unsigned short*)(ws + (54u << 20));      //  8 MB bf16 [N,K]
    float*          sc  = (float*)(ws + (62u << 20));               // 16 KB
    int*            nb  = (int*)(ws + (62u << 20) + 16384);
    int*            posg= (int*)(ws + (62u << 20) + 32768);         // 16 KB

    convert_bf16<<<(B * D_IN) / 1024, 256, 0, stream>>>(x, xb);
    transpose_convert<<<dim3(H / 64, D_IN / 64), 256, 0, stream>>>(W1, W1t, D_IN, H);
    transpose_convert<<<dim3(H / 64, H / 64), 256, 0, stream>>>(W2, W2t, H, H);

    gemm_bf16_mfma<1><<<dim3(H / 128, B / 128), 256, 0, stream>>>(
        xb, W1t, b1, h1, nullptr, B, H, D_IN);
    gemm_bf16_mfma<0><<<dim3(H / 128, B / 128), 256, 0, stream>>>(
        h1, W2t, b2, nullptr, h2, B, H, H);

    matvec_bias<<<B / 4, 256, 0, stream>>>(h2, W3, b3, sc, out + B, H);
    rank_count<<<64, 64, 0, stream>>>(sc, posg);
    pav_fill<<<1, 1024, 0, stream>>>(sc, posg, out, nb);
}

// Round 5
// 208.073 us; speedup vs baseline: 1.3018x; 1.3018x over previous
//
#include <hip/hip_runtime.h>
#include <hip/hip_bf16.h>

typedef float f32x4 __attribute__((ext_vector_type(4)));
typedef __bf16 bf16x8 __attribute__((ext_vector_type(8)));

__device__ __forceinline__ unsigned short f2bf(float f) {
    unsigned u = __float_as_uint(f);
    return (unsigned short)((u + 0x7fffu + ((u >> 16) & 1u)) >> 16);  // RNE
}

// ---------------------------------------------------------------------------
// Elementwise fp32 -> bf16 (n multiple of 1024).
// ---------------------------------------------------------------------------
__global__ __launch_bounds__(256) void convert_bf16(
    const float* __restrict__ in, unsigned short* __restrict__ out)
{
    int i = (blockIdx.x * 256 + threadIdx.x) * 4;
    float4 v = *(const float4*)(in + i);
    ushort4 o = { f2bf(v.x), f2bf(v.y), f2bf(v.z), f2bf(v.w) };
    *(ushort4*)(out + i) = o;
}

// ---------------------------------------------------------------------------
// W [K,N] fp32 row-major  ->  Wt [N,K] bf16 row-major. 64x64 LDS tiles.
// ---------------------------------------------------------------------------
__global__ __launch_bounds__(256) void transpose_convert(
    const float* __restrict__ W, unsigned short* __restrict__ Wt, int K, int N)
{
    __shared__ float tile[64][65];
    const int bx = blockIdx.x;   // n tile
    const int by = blockIdx.y;   // k tile
    const int t = threadIdx.x;
    const int col4 = t & 15;
    const int row  = t >> 4;

    #pragma unroll
    for (int i = 0; i < 4; ++i) {
        int r = row + i * 16;
        float4 v = *(const float4*)(W + (size_t)(by * 64 + r) * N + bx * 64 + col4 * 4);
        tile[r][col4 * 4 + 0] = v.x;
        tile[r][col4 * 4 + 1] = v.y;
        tile[r][col4 * 4 + 2] = v.z;
        tile[r][col4 * 4 + 3] = v.w;
    }
    __syncthreads();
    #pragma unroll
    for (int i = 0; i < 4; ++i) {
        int r = row + i * 16;
        ushort4 o = { f2bf(tile[col4 * 4 + 0][r]), f2bf(tile[col4 * 4 + 1][r]),
                      f2bf(tile[col4 * 4 + 2][r]), f2bf(tile[col4 * 4 + 3][r]) };
        *(ushort4*)(Wt + (size_t)(bx * 64 + r) * K + by * 64 + col4 * 4) = o;
    }
}

// ---------------------------------------------------------------------------
// bf16 MFMA GEMM (m97 structure): C = relu(A @ Bt^T + bias).
// ---------------------------------------------------------------------------
template <int OUT_BF16>
__global__ __launch_bounds__(256) void gemm_bf16_mfma(
    const unsigned short* __restrict__ A, const unsigned short* __restrict__ Bt,
    const float* __restrict__ bias, unsigned short* __restrict__ Cbf,
    float* __restrict__ Cf, int M, int N, int K)
{
    __shared__ unsigned short As[128 * 32];
    __shared__ unsigned short Bs[128 * 32];

    const int tid = threadIdx.x;
    const int wave = tid >> 6;
    const int lane = tid & 63;
    const int bn = blockIdx.x, bm = blockIdx.y;
    const int wm = (wave & 1) * 64;
    const int wn = (wave >> 1) * 64;

    const unsigned short* Ablk = A  + (size_t)(bm * 128) * K;
    const unsigned short* Bblk = Bt + (size_t)(bn * 128) * K;

    const int srow0 = wave * 32;
    const int lrow = lane >> 2;
    const int lcol = (lane & 3) * 8;

    f32x4 acc[4][4] = {};

    for (int k0 = 0; k0 < K; k0 += 32) {
        #pragma unroll
        for (int j = 0; j < 2; ++j) {
            int r = srow0 + j * 16 + lrow;
            __builtin_amdgcn_global_load_lds(
                (const __attribute__((address_space(1))) void*)(Ablk + (size_t)r * K + k0 + lcol),
                (__attribute__((address_space(3))) void*)(As + (srow0 + j * 16) * 32),
                16, 0, 0);
            __builtin_amdgcn_global_load_lds(
                (const __attribute__((address_space(1))) void*)(Bblk + (size_t)r * K + k0 + lcol),
                (__attribute__((address_space(3))) void*)(Bs + (srow0 + j * 16) * 32),
                16, 0, 0);
        }
        __syncthreads();

        bf16x8 a[4], b[4];
        #pragma unroll
        for (int mt = 0; mt < 4; ++mt)
            a[mt] = *(const bf16x8*)(As + (wm + mt * 16 + (lane & 15)) * 32 + (lane >> 4) * 8);
        #pragma unroll
        for (int nt = 0; nt < 4; ++nt)
            b[nt] = *(const bf16x8*)(Bs + (wn + nt * 16 + (lane & 15)) * 32 + (lane >> 4) * 8);
        #pragma unroll
        for (int mt = 0; mt < 4; ++mt)
            #pragma unroll
            for (int nt = 0; nt < 4; ++nt)
                acc[mt][nt] = __builtin_amdgcn_mfma_f32_16x16x32_bf16(
                    a[mt], b[nt], acc[mt][nt], 0, 0, 0);
        __syncthreads();
    }

    const int cm0 = bm * 128 + wm;
    const int cn0 = bn * 128 + wn;
    const int lc = lane & 15;
    const int lr = (lane >> 4) * 4;
    #pragma unroll
    for (int nt = 0; nt < 4; ++nt) {
        float bv = bias[cn0 + nt * 16 + lc];
        #pragma unroll
        for (int mt = 0; mt < 4; ++mt) {
            #pragma unroll
            for (int r = 0; r < 4; ++r) {
                float v = fmaxf(acc[mt][nt][r] + bv, 0.0f);
                size_t idx = (size_t)(cm0 + mt * 16 + lr + r) * N + cn0 + nt * 16 + lc;
                if (OUT_BF16) Cbf[idx] = f2bf(v);
                else          Cf[idx] = v;
            }
        }
    }
}

// ---------------------------------------------------------------------------
// Layer 3: scores[r] = dot(H[r,:], W3) + b3.  One wave per row, fp32.
// Also emits the stable-descending sort key for row r:
//   key = (~asc_map(score) << 12) | r   (distinct; ties break by index asc).
// ---------------------------------------------------------------------------
__global__ __launch_bounds__(256) void matvec_bias(
    const float* __restrict__ H, const float* __restrict__ W,
    const float* __restrict__ b3, float* __restrict__ scores,
    float* __restrict__ out_scores, unsigned long long* __restrict__ keys, int N)
{
    const int wave = threadIdx.x >> 6;
    const int lane = threadIdx.x & 63;
    const int row  = blockIdx.x * 4 + wave;
    const float* h = H + (size_t)row * N;

    float s = 0.0f;
    for (int w = 0; w < N / 256; ++w) {
        float4 v = *(const float4*)(h + w * 256 + lane * 4);
        float4 g = *(const float4*)(W + w * 256 + lane * 4);
        s += v.x * g.x + v.y * g.y + v.z * g.z + v.w * g.w;
    }
    #pragma unroll
    for (int off = 32; off > 0; off >>= 1) s += __shfl_down(s, off);
    if (lane == 0) {
        float r = s + b3[0];
        scores[row] = r;
        out_scores[row] = r;
        unsigned ub = __float_as_uint(r);
        unsigned m  = (ub & 0x80000000u) ? ~ub : (ub | 0x80000000u); // asc map
        unsigned d  = ~m;                                            // desc map
        keys[row] = ((unsigned long long)d << 12) | (unsigned)row;
    }
}

// ---------------------------------------------------------------------------
// Stable-descending argsort position, 2-D tiled counting:
// block (bi,bj): i in [bi*256,..+256), j in [bj*256,..+256).
// 256 threads (4 waves) stage 256 j-keys in LDS; thread t counts
// kj[j] < keys[i] over the tile; atomicAdd partial into posg[i].
// ---------------------------------------------------------------------------
__global__ __launch_bounds__(256) void rank_count(
    const unsigned long long* __restrict__ keys, int* __restrict__ posg)
{
    __shared__ unsigned long long kj[256];
    const int t = threadIdx.x;
    const int i = blockIdx.x * 256 + t;
    kj[t] = keys[blockIdx.y * 256 + t];
    const unsigned long long mykey = keys[i];
    __syncthreads();

    int cnt = 0;
    #pragma unroll 32
    for (int j = 0; j < 256; ++j)
        cnt += (kj[j] < mykey) ? 1 : 0;
    atomicAdd(&posg[i], cnt);
}

// ---------------------------------------------------------------------------
// PAV + fill, single block of 1024 threads.
//   svals[pos[i]] = z_i (LDS scatter) -> chunked PAV (64 chunks x 64, then
//   serial merge of block lists; PAV is associative over pooled blocks) ->
//   rank[i] = svals[pos[i]] - mean(block containing pos[i])  (coalesced).
// LDS: bsum f64[4096] 32K | svals f32[4096] 16K | bstart u16[4096] 8K |
//      plds u16[4096] 8K  = 64 KB. nb broadcast via ws int.
// ---------------------------------------------------------------------------
__global__ __launch_bounds__(1024) void pav_fill(
    const float* __restrict__ scores, const int* __restrict__ posg,
    float* __restrict__ rank_out, int* nb_ws)
{
    constexpr int n = 4096;
    __shared__ __align__(16) unsigned char lds[65536];
    double* bsum  = (double*)lds;
    float*  svals = (float*)(lds + 32768);
    unsigned short* bstart = (unsigned short*)(lds + 49152);
    unsigned short* plds   = (unsigned short*)(lds + 57344);

    const int tid = threadIdx.x;

    for (int t = tid; t < n; t += 1024) {
        int p = posg[t];
        svals[p] = scores[t];
        plds[t] = (unsigned short)p;
    }
    __syncthreads();

    // ---- Phase A: per-chunk PAV, 64 threads, chunk c = tid ----
    if (tid < 64) {
        const int base = tid << 6;
        int depth = 0;
        double rtsum = 0.0; int rtstart = 0;
        for (int s = 0; s < 64; ++s) {
            int i = base + s;
            double csum = (double)svals[i] - (double)(n - i);   // y_i
            int cs = i;
            const int ce = i + 1;
            while (depth > 0) {
                if (rtsum * (double)(ce - cs) <= csum * (double)(cs - rtstart)) {
                    csum += rtsum; cs = rtstart; depth--;
                    if (depth > 0) {
                        rtsum = bsum[base + depth - 1];
                        rtstart = bstart[base + depth - 1];
                    }
                } else break;
            }
            if (depth > 0) {
                bsum[base + depth - 1] = rtsum;
                bstart[base + depth - 1] = (unsigned short)rtstart;
            }
            rtsum = csum; rtstart = cs; depth++;
        }
        bsum[base + depth - 1] = rtsum;
        bstart[base + depth - 1] = (unsigned short)rtstart;
        if (depth < 64) bstart[base + depth] = 0xFFFFu;   // sentinel
    }
    __syncthreads();

    // ---- Phase B: serial merge of chunk block lists (thread 0) ----
    if (tid == 0) {
        int g = 0;
        double gtsum = 0.0; int gtstart = 0;
        for (int c = 0; c < 64; ++c) {
            const int base = c << 6;
            for (int s = 0; s < 64; ++s) {
                const int r = base + s;
                int cs = bstart[r];
                if (cs == 0xFFFF) break;
                int ce;
                if (s < 63) {
                    int nx = bstart[r + 1];
                    ce = (nx == 0xFFFF) ? base + 64 : nx;
                } else ce = base + 64;
                double csum = bsum[r];
                while (g > 0) {
                    if (gtsum * (double)(ce - cs) <= csum * (double)(cs - gtstart)) {
                        csum += gtsum; cs = gtstart; g--;
                        if (g > 0) { gtsum = bsum[g - 1]; gtstart = bstart[g - 1]; }
                    } else break;
                }
                if (g > 0) {
                    bsum[g - 1] = gtsum;
                    bstart[g - 1] = (unsigned short)gtstart;
                }
                gtsum = csum; gtstart = cs; g++;
            }
        }
        bsum[g - 1] = gtsum;
        bstart[g - 1] = (unsigned short)gtstart;
        __hip_atomic_store(nb_ws, g, __ATOMIC_RELEASE, __HIP_MEMORY_SCOPE_AGENT);
    }
    __syncthreads();
    const int nb = __hip_atomic_load(nb_ws, __ATOMIC_ACQUIRE, __HIP_MEMORY_SCOPE_AGENT);

    // ---- gather: rank[i] = svals[p] - mean(block(p)), coalesced writes ----
    for (int t = tid; t < n; t += 1024) {
        int p = plds[t];
        int lo = 0, hi = nb - 1;
        while (lo < hi) {
            int mid = (lo + hi + 1) >> 1;
            if ((int)bstart[mid] <= p) lo = mid; else hi = mid - 1;
        }
        int bs = bstart[lo];
        int be = (lo + 1 < nb) ? (int)bstart[lo + 1] : n;
        float mean = (float)(bsum[lo] / (double)(be - bs));
        rank_out[t] = svals[p] - mean;
    }
}

// ---------------------------------------------------------------------------
extern "C" void kernel_launch(void* const* d_in, const int* in_sizes, int n_in,
                              void* d_out, int out_size, void* d_ws, size_t ws_size,
                              hipStream_t stream) {
    const float* x  = (const float*)d_in[0];
    const float* W1 = (const float*)d_in[1];
    const float* b1 = (const float*)d_in[2];
    const float* W2 = (const float*)d_in[3];
    const float* b2 = (const float*)d_in[4];
    const float* W3 = (const float*)d_in[5];
    const float* b3 = (const float*)d_in[6];
    float* out = (float*)d_out;   // [0,4096): rank, [4096,8192): scores

    const int B = 4096, D_IN = 512, H = 2048;

    char* ws = (char*)d_ws;
    unsigned short* h1  = (unsigned short*)(ws);                    // 16 MB bf16
    float*          h2  = (float*)(ws + (16u << 20));               // 32 MB fp32
    unsigned short* xb  = (unsigned short*)(ws + (48u << 20));      //  4 MB bf16
    unsigned short* W1t = (unsigned short*)(ws + (52u << 20));      //  2 MB bf16 [N,K]
    unsigned short* W2t = (unsigned short*)(ws + (54u << 20));      //  8 MB bf16 [N,K]
    float*          sc  = (float*)(ws + (62u << 20));               // 16 KB
    int*            nb  = (int*)(ws + (62u << 20) + 16384);
    int*            posg= (int*)(ws + (62u << 20) + 32768);         // 16 KB
    unsigned long long* keys = (unsigned long long*)(ws + (62u << 20) + 65536); // 32 KB

    convert_bf16<<<(B * D_IN) / 1024, 256, 0, stream>>>(x, xb);
    transpose_convert<<<dim3(H / 64, D_IN / 64), 256, 0, stream>>>(W1, W1t, D_IN, H);
    transpose_convert<<<dim3(H / 64, H / 64), 256, 0, stream>>>(W2, W2t, H, H);

    gemm_bf16_mfma<1><<<dim3(H / 128, B / 128), 256, 0, stream>>>(
        xb, W1t, b1, h1, nullptr, B, H, D_IN);
    gemm_bf16_mfma<0><<<dim3(H / 128, B / 128), 256, 0, stream>>>(
        h1, W2t, b2, nullptr, h2, B, H, H);

    matvec_bias<<<B / 4, 256, 0, stream>>>(h2, W3, b3, sc, out + B, keys, H);

    hipMemsetAsync(posg, 0, B * sizeof(int), stream);
    rank_count<<<dim3(B / 256, B / 256), 256, 0, stream>>>(keys, posg);
    pav_fill<<<1, 1024, 0, stream>>>(sc, posg, out, nb);
}

// Round 6
// 200.296 us; speedup vs baseline: 1.3524x; 1.0388x over previous
//
#include <hip/hip_runtime.h>
#include <hip/hip_bf16.h>

typedef float f32x4 __attribute__((ext_vector_type(4)));
typedef __bf16 bf16x8 __attribute__((ext_vector_type(8)));

__device__ __forceinline__ unsigned short f2bf(float f) {
    unsigned u = __float_as_uint(f);
    return (unsigned short)((u + 0x7fffu + ((u >> 16) & 1u)) >> 16);  // RNE
}

// ---------------------------------------------------------------------------
// Elementwise fp32 -> bf16 (n multiple of 1024).
// ---------------------------------------------------------------------------
__global__ __launch_bounds__(256) void convert_bf16(
    const float* __restrict__ in, unsigned short* __restrict__ out)
{
    int i = (blockIdx.x * 256 + threadIdx.x) * 4;
    float4 v = *(const float4*)(in + i);
    ushort4 o = { f2bf(v.x), f2bf(v.y), f2bf(v.z), f2bf(v.w) };
    *(ushort4*)(out + i) = o;
}

// ---------------------------------------------------------------------------
// Transpose+convert both weights in ONE dispatch.
// W [K,N] fp32 row-major -> Wt [N,K] bf16 row-major, 64x64 LDS tiles.
// grid (32, 8+32): by<8 -> W1 (K=512,N=2048); else W2 (K=2048,N=2048).
// ---------------------------------------------------------------------------
__device__ __forceinline__ void transpose_tile(
    const float* __restrict__ W, unsigned short* __restrict__ Wt,
    int K, int N, int bx, int by, float (*tile)[65])
{
    const int t = threadIdx.x;
    const int col4 = t & 15;
    const int row  = t >> 4;

    #pragma unroll
    for (int i = 0; i < 4; ++i) {
        int r = row + i * 16;
        float4 v = *(const float4*)(W + (size_t)(by * 64 + r) * N + bx * 64 + col4 * 4);
        tile[r][col4 * 4 + 0] = v.x;
        tile[r][col4 * 4 + 1] = v.y;
        tile[r][col4 * 4 + 2] = v.z;
        tile[r][col4 * 4 + 3] = v.w;
    }
    __syncthreads();
    #pragma unroll
    for (int i = 0; i < 4; ++i) {
        int r = row + i * 16;
        ushort4 o = { f2bf(tile[col4 * 4 + 0][r]), f2bf(tile[col4 * 4 + 1][r]),
                      f2bf(tile[col4 * 4 + 2][r]), f2bf(tile[col4 * 4 + 3][r]) };
        *(ushort4*)(Wt + (size_t)(bx * 64 + r) * K + by * 64 + col4 * 4) = o;
    }
}

__global__ __launch_bounds__(256) void prep_weights(
    const float* __restrict__ W1, unsigned short* __restrict__ W1t,
    const float* __restrict__ W2, unsigned short* __restrict__ W2t)
{
    __shared__ float tile[64][65];
    if (blockIdx.y < 8)
        transpose_tile(W1, W1t, 512, 2048, blockIdx.x, blockIdx.y, tile);
    else
        transpose_tile(W2, W2t, 2048, 2048, blockIdx.x, blockIdx.y - 8, tile);
}

// ---------------------------------------------------------------------------
// bf16 MFMA GEMM (m97 structure) with XOR-swizzled LDS to kill the 8-way
// bank conflict on fragment reads:  LDS(r,c) = global(r, c ^ ((r>>1)&3)),
// c = 16B chunk index (4 chunks per 64B row of BK=32 bf16). Swizzle applied
// on the GLOBAL side of global_load_lds (LDS side must stay lane-linear).
// All swizzle terms are lane-only -> loop-invariant, no per-iter VALU.
//
// MODE 0: C = relu(A@Bt^T + bias) stored bf16 (layer 1).
// MODE 1: fused layer-3: p_row = sum_col relu(acc+bias)*w3[col]; 16-lane
//         shuffle reduce; atomicAdd into scores[row]. No C materialized.
// ---------------------------------------------------------------------------
template <int MODE>
__global__ __launch_bounds__(256) void gemm_bf16_mfma(
    const unsigned short* __restrict__ A, const unsigned short* __restrict__ Bt,
    const float* __restrict__ bias, unsigned short* __restrict__ Cbf,
    const float* __restrict__ w3, float* __restrict__ scores,
    int M, int N, int K)
{
    __shared__ unsigned short As[128 * 32];
    __shared__ unsigned short Bs[128 * 32];

    const int tid = threadIdx.x;
    const int wave = tid >> 6;
    const int lane = tid & 63;
    const int bn = blockIdx.x, bm = blockIdx.y;
    const int wm = (wave & 1) * 64;
    const int wn = (wave >> 1) * 64;

    const unsigned short* Ablk = A  + (size_t)(bm * 128) * K;
    const unsigned short* Bblk = Bt + (size_t)(bn * 128) * K;

    const int srow0 = wave * 32;
    const int lrow = lane >> 2;                                   // 0..15
    const int lcol = (((lane & 3) ^ ((lane >> 3) & 3))) * 8;      // swizzled chunk

    f32x4 acc[4][4] = {};

    for (int k0 = 0; k0 < K; k0 += 32) {
        #pragma unroll
        for (int j = 0; j < 2; ++j) {
            int r = srow0 + j * 16 + lrow;
            __builtin_amdgcn_global_load_lds(
                (const __attribute__((address_space(1))) void*)(Ablk + (size_t)r * K + k0 + lcol),
                (__attribute__((address_space(3))) void*)(As + (srow0 + j * 16) * 32),
                16, 0, 0);
            __builtin_amdgcn_global_load_lds(
                (const __attribute__((address_space(1))) void*)(Bblk + (size_t)r * K + k0 + lcol),
                (__attribute__((address_space(3))) void*)(Bs + (srow0 + j * 16) * 32),
                16, 0, 0);
        }
        __syncthreads();

        // fragment read: chunk c = h ^ ((row>>1)&3), h = lane>>4; row bits
        // 1,2 == lane bits 1,2 (row base multiple of 16) -> lane-only expr.
        const int rsw = (((lane >> 4) ^ ((lane >> 1) & 3))) * 8;
        bf16x8 a[4], b[4];
        #pragma unroll
        for (int mt = 0; mt < 4; ++mt)
            a[mt] = *(const bf16x8*)(As + (wm + mt * 16 + (lane & 15)) * 32 + rsw);
        #pragma unroll
        for (int nt = 0; nt < 4; ++nt)
            b[nt] = *(const bf16x8*)(Bs + (wn + nt * 16 + (lane & 15)) * 32 + rsw);
        #pragma unroll
        for (int mt = 0; mt < 4; ++mt)
            #pragma unroll
            for (int nt = 0; nt < 4; ++nt)
                acc[mt][nt] = __builtin_amdgcn_mfma_f32_16x16x32_bf16(
                    a[mt], b[nt], acc[mt][nt], 0, 0, 0);
        __syncthreads();
    }

    // Epilogue. C/D frag: col = lane&15, row = (lane>>4)*4 + reg  [m89]
    const int cm0 = bm * 128 + wm;
    const int cn0 = bn * 128 + wn;
    const int lc = lane & 15;
    const int lr = (lane >> 4) * 4;

    if (MODE == 0) {
        #pragma unroll
        for (int nt = 0; nt < 4; ++nt) {
            float bv = bias[cn0 + nt * 16 + lc];
            #pragma unroll
            for (int mt = 0; mt < 4; ++mt) {
                #pragma unroll
                for (int r = 0; r < 4; ++r) {
                    float v = fmaxf(acc[mt][nt][r] + bv, 0.0f);
                    size_t idx = (size_t)(cm0 + mt * 16 + lr + r) * N + cn0 + nt * 16 + lc;
                    Cbf[idx] = f2bf(v);
                }
            }
        }
    } else {
        float bv[4], w3v[4];
        #pragma unroll
        for (int nt = 0; nt < 4; ++nt) {
            bv[nt]  = bias[cn0 + nt * 16 + lc];
            w3v[nt] = w3[cn0 + nt * 16 + lc];
        }
        #pragma unroll
        for (int mt = 0; mt < 4; ++mt) {
            #pragma unroll
            for (int r = 0; r < 4; ++r) {
                float p = 0.0f;
                #pragma unroll
                for (int nt = 0; nt < 4; ++nt)
                    p += fmaxf(acc[mt][nt][r] + bv[nt], 0.0f) * w3v[nt];
                p += __shfl_xor(p, 1);
                p += __shfl_xor(p, 2);
                p += __shfl_xor(p, 4);
                p += __shfl_xor(p, 8);
                if (lc == 0)
                    atomicAdd(&scores[cm0 + mt * 16 + lr + r], p);
            }
        }
    }
}

// ---------------------------------------------------------------------------
// scores += b3; emit out_scores and stable-descending sort keys:
//   key = (~asc_map(score) << 12) | i  (distinct; ties break by index asc).
// ---------------------------------------------------------------------------
__global__ __launch_bounds__(256) void finalize_scores(
    float* __restrict__ sc, const float* __restrict__ b3,
    float* __restrict__ out_scores, unsigned long long* __restrict__ keys)
{
    int t = blockIdx.x * 256 + threadIdx.x;
    float v = sc[t] + b3[0];
    sc[t] = v;
    out_scores[t] = v;
    unsigned ub = __float_as_uint(v);
    unsigned m  = (ub & 0x80000000u) ? ~ub : (ub | 0x80000000u);
    unsigned d  = ~m;
    keys[t] = ((unsigned long long)d << 12) | (unsigned)t;
}

// ---------------------------------------------------------------------------
// Stable-descending argsort position, 2-D tiled counting (256 blocks, 4
// waves each): block (bi,bj) stages 256 j-keys in LDS, thread t counts
// kj[j] < keys[i], atomicAdd partial into posg[i].
// ---------------------------------------------------------------------------
__global__ __launch_bounds__(256) void rank_count(
    const unsigned long long* __restrict__ keys, int* __restrict__ posg)
{
    __shared__ unsigned long long kj[256];
    const int t = threadIdx.x;
    const int i = blockIdx.x * 256 + t;
    kj[t] = keys[blockIdx.y * 256 + t];
    const unsigned long long mykey = keys[i];
    __syncthreads();

    int cnt = 0;
    #pragma unroll 32
    for (int j = 0; j < 256; ++j)
        cnt += (kj[j] < mykey) ? 1 : 0;
    atomicAdd(&posg[i], cnt);
}

// ---------------------------------------------------------------------------
// PAV + fill, single block of 1024 threads (chunked PAV, verified R2-R5).
// ---------------------------------------------------------------------------
__global__ __launch_bounds__(1024) void pav_fill(
    const float* __restrict__ scores, const int* __restrict__ posg,
    float* __restrict__ rank_out, int* nb_ws)
{
    constexpr int n = 4096;
    __shared__ __align__(16) unsigned char lds[65536];
    double* bsum  = (double*)lds;
    float*  svals = (float*)(lds + 32768);
    unsigned short* bstart = (unsigned short*)(lds + 49152);
    unsigned short* plds   = (unsigned short*)(lds + 57344);

    const int tid = threadIdx.x;

    for (int t = tid; t < n; t += 1024) {
        int p = posg[t];
        svals[p] = scores[t];
        plds[t] = (unsigned short)p;
    }
    __syncthreads();

    // ---- Phase A: per-chunk PAV, 64 threads, chunk c = tid ----
    if (tid < 64) {
        const int base = tid << 6;
        int depth = 0;
        double rtsum = 0.0; int rtstart = 0;
        for (int s = 0; s < 64; ++s) {
            int i = base + s;
            double csum = (double)svals[i] - (double)(n - i);   // y_i
            int cs = i;
            const int ce = i + 1;
            while (depth > 0) {
                if (rtsum * (double)(ce - cs) <= csum * (double)(cs - rtstart)) {
                    csum += rtsum; cs = rtstart; depth--;
                    if (depth > 0) {
                        rtsum = bsum[base + depth - 1];
                        rtstart = bstart[base + depth - 1];
                    }
                } else break;
            }
            if (depth > 0) {
                bsum[base + depth - 1] = rtsum;
                bstart[base + depth - 1] = (unsigned short)rtstart;
            }
            rtsum = csum; rtstart = cs; depth++;
        }
        bsum[base + depth - 1] = rtsum;
        bstart[base + depth - 1] = (unsigned short)rtstart;
        if (depth < 64) bstart[base + depth] = 0xFFFFu;   // sentinel
    }
    __syncthreads();

    // ---- Phase B: serial merge of chunk block lists (thread 0) ----
    if (tid == 0) {
        int g = 0;
        double gtsum = 0.0; int gtstart = 0;
        for (int c = 0; c < 64; ++c) {
            const int base = c << 6;
            for (int s = 0; s < 64; ++s) {
                const int r = base + s;
                int cs = bstart[r];
                if (cs == 0xFFFF) break;
                int ce;
                if (s < 63) {
                    int nx = bstart[r + 1];
                    ce = (nx == 0xFFFF) ? base + 64 : nx;
                } else ce = base + 64;
                double csum = bsum[r];
                while (g > 0) {
                    if (gtsum * (double)(ce - cs) <= csum * (double)(cs - gtstart)) {
                        csum += gtsum; cs = gtstart; g--;
                        if (g > 0) { gtsum = bsum[g - 1]; gtstart = bstart[g - 1]; }
                    } else break;
                }
                if (g > 0) {
                    bsum[g - 1] = gtsum;
                    bstart[g - 1] = (unsigned short)gtstart;
                }
                gtsum = csum; gtstart = cs; g++;
            }
        }
        bsum[g - 1] = gtsum;
        bstart[g - 1] = (unsigned short)gtstart;
        __hip_atomic_store(nb_ws, g, __ATOMIC_RELEASE, __HIP_MEMORY_SCOPE_AGENT);
    }
    __syncthreads();
    const int nb = __hip_atomic_load(nb_ws, __ATOMIC_ACQUIRE, __HIP_MEMORY_SCOPE_AGENT);

    // ---- gather: rank[i] = svals[p] - mean(block(p)), coalesced writes ----
    for (int t = tid; t < n; t += 1024) {
        int p = plds[t];
        int lo = 0, hi = nb - 1;
        while (lo < hi) {
            int mid = (lo + hi + 1) >> 1;
            if ((int)bstart[mid] <= p) lo = mid; else hi = mid - 1;
        }
        int bs = bstart[lo];
        int be = (lo + 1 < nb) ? (int)bstart[lo + 1] : n;
        float mean = (float)(bsum[lo] / (double)(be - bs));
        rank_out[t] = svals[p] - mean;
    }
}

// ---------------------------------------------------------------------------
extern "C" void kernel_launch(void* const* d_in, const int* in_sizes, int n_in,
                              void* d_out, int out_size, void* d_ws, size_t ws_size,
                              hipStream_t stream) {
    const float* x  = (const float*)d_in[0];
    const float* W1 = (const float*)d_in[1];
    const float* b1 = (const float*)d_in[2];
    const float* W2 = (const float*)d_in[3];
    const float* b2 = (const float*)d_in[4];
    const float* W3 = (const float*)d_in[5];
    const float* b3 = (const float*)d_in[6];
    float* out = (float*)d_out;   // [0,4096): rank, [4096,8192): scores

    const int B = 4096, D_IN = 512, H = 2048;

    char* ws = (char*)d_ws;
    unsigned short* h1  = (unsigned short*)(ws);                    // 16 MB bf16
    unsigned short* xb  = (unsigned short*)(ws + (16u << 20));      //  4 MB bf16
    unsigned short* W1t = (unsigned short*)(ws + (20u << 20));      //  2 MB bf16 [N,K]
    unsigned short* W2t = (unsigned short*)(ws + (22u << 20));      //  8 MB bf16 [N,K]
    float*          sc  = (float*)(ws + (30u << 20));               // 16 KB
    int*            posg= (int*)(ws + (30u << 20) + 16384);         // 16 KB
    unsigned long long* keys = (unsigned long long*)(ws + (30u << 20) + 32768); // 32 KB
    int*            nb  = (int*)(ws + (30u << 20) + 65536);

    convert_bf16<<<(B * D_IN) / 1024, 256, 0, stream>>>(x, xb);
    prep_weights<<<dim3(32, 40), 256, 0, stream>>>(W1, W1t, W2, W2t);

    // zero scores (atomic accumulator) + posg in one memset: contiguous 32 KB
    hipMemsetAsync(sc, 0, 32768, stream);

    // GEMM1: h1 = relu(x @ W1 + b1), bf16. M=4096 N=2048 K=512.
    gemm_bf16_mfma<0><<<dim3(H / 128, B / 128), 256, 0, stream>>>(
        xb, W1t, b1, h1, nullptr, nullptr, B, H, D_IN);
    // GEMM2 fused with layer-3 matvec: scores += relu(h1@W2+b2) @ W3.
    gemm_bf16_mfma<1><<<dim3(H / 128, B / 128), 256, 0, stream>>>(
        h1, W2t, b2, nullptr, W3, sc, B, H, H);

    finalize_scores<<<B / 256, 256, 0, stream>>>(sc, b3, out + B, keys);
    rank_count<<<dim3(B / 256, B / 256), 256, 0, stream>>>(keys, posg);
    pav_fill<<<1, 1024, 0, stream>>>(sc, posg, out, nb);
}